// Round 6
// baseline (16423.491 us; speedup 1.0000x reference)
//
#include <hip/hip_runtime.h>
#include <cstdint>
#include <cstddef>

// Problem constants
#define BB 256     // batch
#define TT 512     // time steps
#define HH 512     // hidden
// 256 blocks = 4 m-groups (64 batch rows) x 64 s-slices (8 h-cols = 32 gatecols/layer).
// Weights LDS-resident. c-state in regs. ct redundant per block (LDS-local).
// h exchange: BLOCKED layout [par][m][slice][row][8] -> each block's publish is one
// contiguous 1KB coalesced region (full 64B lines, no RMW). h0_prev is register-carried
// across steps (no reload). x(t+1) prefetched mid-L1.
// Flags: relaxed agent atomics + wave-local vmcnt(0) before add (R5-proven mechanism);
// the only cache-maintaining release/acquire is the one-time startup barrier.

typedef _Float16 f16;
typedef _Float16 f16x8 __attribute__((ext_vector_type(8)));
typedef float f32x4 __attribute__((ext_vector_type(4)));

union U16B { uint64_t u[2]; f16x8 v; };

// ---------------- threefry2x32 (key = (0,42)), jax_threefry_partitionable ----------------
__device__ __forceinline__ void tf_round(uint32_t& x0, uint32_t& x1, const int r) {
  x0 += x1;
  x1 = (x1 << r) | (x1 >> (32 - r));
  x1 ^= x0;
}

__device__ __forceinline__ void threefry2x32(uint32_t c0, uint32_t c1, uint32_t& o0, uint32_t& o1) {
  const uint32_t ks0 = 0u, ks1 = 42u;
  const uint32_t ks2 = 0x1BD11BDAu ^ ks0 ^ ks1;
  uint32_t x0 = c0 + ks0, x1 = c1 + ks1;
  tf_round(x0,x1,13); tf_round(x0,x1,15); tf_round(x0,x1,26); tf_round(x0,x1,6);
  x0 += ks1; x1 += ks2 + 1u;
  tf_round(x0,x1,17); tf_round(x0,x1,29); tf_round(x0,x1,16); tf_round(x0,x1,24);
  x0 += ks2; x1 += ks0 + 2u;
  tf_round(x0,x1,13); tf_round(x0,x1,15); tf_round(x0,x1,26); tf_round(x0,x1,6);
  x0 += ks0; x1 += ks1 + 3u;
  tf_round(x0,x1,17); tf_round(x0,x1,29); tf_round(x0,x1,16); tf_round(x0,x1,24);
  x0 += ks1; x1 += ks2 + 4u;
  tf_round(x0,x1,13); tf_round(x0,x1,15); tf_round(x0,x1,26); tf_round(x0,x1,6);
  x0 += ks2; x1 += ks0 + 5u;
  o0 = x0; o1 = x1;
}

__device__ __forceinline__ float gumbel_noise(uint32_t idx) {
  uint32_t o0, o1;
  threefry2x32(0u, idx, o0, o1);
  uint32_t bits = o0 ^ o1;
  uint32_t fb = (bits >> 9) | 0x3f800000u;
  float u = __uint_as_float(fb) - 1.0f;
  const float tiny = 1.17549435e-38f;
  u = fmaxf(tiny, u + tiny);
  return -logf(-logf(u));
}

// ---------------- fast transcendentals (err ~1e-6, tolerance 2e-2) ----------------
__device__ __forceinline__ float fsig(float x) {
  return __builtin_amdgcn_rcpf(1.0f + __expf(-x));
}
__device__ __forceinline__ float ftanh(float x) {
  float xx = fminf(fmaxf(x, -15.f), 15.f);
  float t = __expf(2.f * xx);
  return (t - 1.f) * __builtin_amdgcn_rcpf(t + 1.f);
}

// ---------------- atomics (relaxed agent = coherence-point direct) ----------------
__device__ __forceinline__ uint64_t aload64(const f16* p) {
  return __hip_atomic_load((const uint64_t*)p, __ATOMIC_RELAXED, __HIP_MEMORY_SCOPE_AGENT);
}
__device__ __forceinline__ void astore64(f16* p, uint64_t v) {
  __hip_atomic_store((uint64_t*)p, v, __ATOMIC_RELAXED, __HIP_MEMORY_SCOPE_AGENT);
}
__device__ __forceinline__ void flag_add_relaxed(uint32_t* p) {
  __hip_atomic_fetch_add(p, 1u, __ATOMIC_RELAXED, __HIP_MEMORY_SCOPE_AGENT);
}

__device__ __forceinline__ f16x8 cvt8(f32x4 a, f32x4 b) {
  f16x8 w;
  w[0]=(f16)a[0]; w[1]=(f16)a[1]; w[2]=(f16)a[2]; w[3]=(f16)a[3];
  w[4]=(f16)b[0]; w[5]=(f16)b[1]; w[6]=(f16)b[2]; w[7]=(f16)b[3];
  return w;
}

// ---------------- the persistent kernel ----------------
template<bool PRE>
__global__ __launch_bounds__(512, 2) void persistent_kernel(
    const float* __restrict__ states,
    const float* __restrict__ Wih0, const float* __restrict__ Whh0,
    const float* __restrict__ bih0, const float* __restrict__ bhh0,
    const float* __restrict__ Wih1, const float* __restrict__ Whh1,
    const float* __restrict__ bih1, const float* __restrict__ bhh1,
    const float* __restrict__ Wlin, const float* __restrict__ blin,
    float* __restrict__ out,
    uint32_t* cnt0, uint32_t* cntA, uint32_t* cntB,
    f16* h0blk, f16* h1blk, f16* Wlc, float* noise_pre)
{
  __shared__ __align__(16) f16 W0s[32][904];    // 57,856 B
  __shared__ __align__(16) f16 W1s[32][1032];   // 66,048 B
  __shared__ __align__(16) f16 ctl[64][136];    // 17,408 B
  __shared__ __align__(16) f16 Abuf[2][64][72]; // 18,432 B  (total 159,744 <= 160 KiB)
  float (*glds)[36] = reinterpret_cast<float(*)[36]>(&Abuf[0][0][0]);  // alias Abuf[0]
  f16 (*hstage)[8]  = reinterpret_cast<f16(*)[8]>(&Abuf[1][0][0]);     // alias Abuf[1]

  const int tid = threadIdx.x;
  const int bid = blockIdx.x;
  const int m = bid & 3;            // m-group (64 batch rows)
  const int s = bid >> 2;           // h-col slice 0..63 (8 cols)
  const int lane = tid & 63;
  const int wv = tid >> 6;
  const int mu = wv >> 1;           // 16-row tile 0..3
  const int nu = wv & 1;            // 16-gatecol tile (Q: 64-col tile)
  const int ra = lane & 15;
  const int kg = (lane >> 4) << 3;
  const int crow = (lane >> 4) << 2;
  const int srow = tid >> 3;        // staging row 0..63
  const int sk = (tid & 7) << 3;    // staging k offset (f16)
  const int sl8 = tid & 7;          // slice sub-index for blocked h reads
  const int ehc = tid & 7;

  // ---- one-time LDS W init (f32 -> f16, reordered K) ----
  {
    const int lc = tid & 31;
    const int gr = ((lc >> 3) << 9) + s*8 + (lc & 7);   // gate*512 + hcol
    for (int k = tid >> 5; k < 896; k += 16) {
      float v;
      if (k < 256)      v = Wih0[(size_t)gr * 384 + k];              // x
      else if (k < 768) v = Whh0[(size_t)gr * 512 + (k - 256)];      // h0_prev
      else              v = Wih0[(size_t)gr * 384 + 256 + (k - 768)];// ct
      W0s[lc][k] = (f16)v;
    }
    for (int k = tid >> 5; k < 1024; k += 16) {
      float v = (k < 512) ? Whh1[(size_t)gr * 512 + k]               // h1_prev
                          : Wih1[(size_t)gr * 512 + (k - 512)];      // h0_cur
      W1s[lc][k] = (f16)v;
    }
  }
  for (int e = tid; e < 64 * 128; e += 512)
    ctl[e >> 7][e & 127] = (f16)(((e & 15) == 0) ? 1.f : 0.f);

  // ---- global init: Wlc + noise (PLAIN stores; flushed by the startup RELEASE) ----
  if (tid < 128) {
    const int e2 = bid * 128 + tid;
    union { f16 h[2]; uint32_t u; } pk2;
    pk2.h[0] = (f16)Wlin[2*e2]; pk2.h[1] = (f16)Wlin[2*e2 + 1];
    ((uint32_t*)Wlc)[e2] = pk2.u;
  }
  if (PRE) {
    const uint32_t base = (uint32_t)bid * 65536u;
    for (uint32_t e = tid; e < 65536u; e += 512u)
      noise_pre[base + e] = gumbel_noise(base + e);
  }
  // ---- startup barrier: the ONLY cache-maintaining release/acquire ----
  __syncthreads();
  if (tid == 0) {
    __hip_atomic_fetch_add(cnt0, 1u, __ATOMIC_RELEASE, __HIP_MEMORY_SCOPE_AGENT);
    int g = 0;
    while (__hip_atomic_load(cnt0, __ATOMIC_RELAXED, __HIP_MEMORY_SCOPE_AGENT) < 256u && g < 2000000) {
      __builtin_amdgcn_s_sleep(1); ++g;
    }
    (void)__hip_atomic_load(cnt0, __ATOMIC_ACQUIRE, __HIP_MEMORY_SCOPE_AGENT);
  }
  __syncthreads();

  // ---- per-thread constants ----
  const int hcol = s*8 + ehc;
  const float bi0 = bih0[hcol]        + bhh0[hcol];
  const float bf0 = bih0[512 + hcol]  + bhh0[512 + hcol];
  const float bg0 = bih0[1024 + hcol] + bhh0[1024 + hcol];
  const float bo0 = bih0[1536 + hcol] + bhh0[1536 + hcol];
  const float bi1 = bih1[hcol]        + bhh1[hcol];
  const float bf1 = bih1[512 + hcol]  + bhh1[512 + hcol];
  const float bg1 = bih1[1024 + hcol] + bhh1[1024 + hcol];
  const float bo1 = bih1[1536 + hcol] + bhh1[1536 + hcol];
  float blv[4];
  #pragma unroll
  for (int n_ = 0; n_ < 4; ++n_) blv[n_] = blin[nu*64 + n_*16 + ra];
  float c0r = 0.f, c1r = 0.f;

  f32x4 acce, acco;
  U16B h1c[8], h0p[8], h0c[8];
  f32x4 xf[8], xfn[8];

  auto spin = [&](uint32_t* p, uint32_t tgt) {
    if (tid == 0) {
      int g = 0;
      while (__hip_atomic_load(p, __ATOMIC_RELAXED, __HIP_MEMORY_SCOPE_AGENT) < tgt && g < 1000000) {
        __builtin_amdgcn_s_sleep(1); ++g;
      }
    }
    asm volatile("" ::: "memory");   // compiler fence (data is coherence-point direct)
    __syncthreads();
  };
  auto stageA = [&](int buf, f16x8 w) { *(f16x8*)&Abuf[buf][srow][sk] = w; };
  auto mfma2 = [&](const f16* ap, const f16* wp) {
    f16x8 ae = *(const f16x8*)(ap + kg);
    f16x8 ao = *(const f16x8*)(ap + 32 + kg);
    f16x8 be = *(const f16x8*)(wp + kg);
    f16x8 bo = *(const f16x8*)(wp + 32 + kg);
    acce = __builtin_amdgcn_mfma_f32_16x16x32_f16(ae, be, acce, 0, 0, 0);
    acco = __builtin_amdgcn_mfma_f32_16x16x32_f16(ao, bo, acco, 0, 0, 0);
  };

  // blocked-h address helpers (offsets in f16)
  // publish base for block (par, m, s):  ((par*4 + m)*64 + s) * 512
  // read base for (par, m, slice sub sl8): ((par*4 + m)*64 + sl8)*512 + srow*8; chunk q at +q*4096
  auto hpub = [&](f16* buf, int par) { return buf + (size_t)(((par*4 + m)*64 + s) * 512); };
  auto hrd  = [&](f16* buf, int par) { return buf + (size_t)(((par*4 + m)*64 + sl8) * 512 + srow*8); };

  // ---- Q phase for step tq: wait h1(tq), load h1c, GEMM q, gumbel softmax -> ctl + out ----
  auto qphase = [&](int tq) {
    spin(&cntB[(m << 9) + tq], 64u);
    const f16* h1c_b = hrd(h1blk, tq & 1);
    #pragma unroll
    for (int q_ = 0; q_ < 8; ++q_) {
      h1c[q_].u[0] = aload64(h1c_b + q_*4096);
      h1c[q_].u[1] = aload64(h1c_b + q_*4096 + 4);
    }
    float nz[4][4];
    if (PRE) {
      const float* npp = noise_pre + ((size_t)tq*256 + m*64 + mu*16 + crow)*128 + nu*64 + ra;
      #pragma unroll
      for (int n_ = 0; n_ < 4; ++n_)
        #pragma unroll
        for (int r = 0; r < 4; ++r) nz[n_][r] = npp[(size_t)r*128 + n_*16];
    }
    const f16* wq = Wlc + (size_t)(nu*64 + ra) * 512 + kg;
    f16x8 bE[2][4], bO[2][4];
    #pragma unroll
    for (int n_ = 0; n_ < 4; ++n_) {
      bE[0][n_] = *(const f16x8*)(wq + n_*8192);
      bO[0][n_] = *(const f16x8*)(wq + n_*8192 + 32);
    }
    f32x4 accq[4] = {{0,0,0,0},{0,0,0,0},{0,0,0,0},{0,0,0,0}};
    stageA(0, h1c[0].v);
    __syncthreads();
    #pragma unroll
    for (int j = 0; j < 8; ++j) {
      const int jn = j + 1;
      if (jn < 8) stageA(jn & 1, h1c[jn].v);
      if (j < 7) {
        #pragma unroll
        for (int n_ = 0; n_ < 4; ++n_) {
          bE[jn & 1][n_] = *(const f16x8*)(wq + n_*8192 + jn*64);
          bO[jn & 1][n_] = *(const f16x8*)(wq + n_*8192 + jn*64 + 32);
        }
      }
      f16x8 ae = *(const f16x8*)&Abuf[j & 1][mu*16 + ra][kg];
      f16x8 ao = *(const f16x8*)&Abuf[j & 1][mu*16 + ra][32 + kg];
      #pragma unroll
      for (int n_ = 0; n_ < 4; ++n_) {
        accq[n_] = __builtin_amdgcn_mfma_f32_16x16x32_f16(ae, bE[j & 1][n_], accq[n_], 0, 0, 0);
        accq[n_] = __builtin_amdgcn_mfma_f32_16x16x32_f16(ao, bO[j & 1][n_], accq[n_], 0, 0, 0);
      }
      __syncthreads();
    }
    #pragma unroll
    for (int n_ = 0; n_ < 4; ++n_) {
      const int qc = nu*64 + n_*16 + ra;
      #pragma unroll
      for (int r = 0; r < 4; ++r) {
        const int rl = mu*16 + crow + r;
        float g;
        if (PRE) g = nz[n_][r];
        else {
          const uint32_t nidx = (((uint32_t)tq * 256u + (uint32_t)(m*64 + rl)) * 128u + (uint32_t)qc);
          g = gumbel_noise(nidx);
        }
        float v = (accq[n_][r] + blv[n_] + g) * 10.0f;
        float mx = v;
        #pragma unroll
        for (int k_ = 1; k_ < 16; k_ <<= 1) mx = fmaxf(mx, __shfl_xor(mx, k_));
        float ex = __expf(v - mx);
        float sm = ex;
        #pragma unroll
        for (int k_ = 1; k_ < 16; k_ <<= 1) sm += __shfl_xor(sm, k_);
        float y = ex * __builtin_amdgcn_rcpf(sm);
        ctl[rl][qc] = (f16)y;
      }
    }
    __syncthreads();   // ctl final
    if (tid < 128)     // this block publishes exactly batch row m*64+s (coalesced 512 B)
      out[((size_t)(m*64 + s) * TT + tq) * 128 + tid] = (float)ctl[s][tid];
  };

  // ---- prologue: x(0) loads; h0_prev = 0 regs ----
  {
    const float* x_b0 = states + ((size_t)(m*64 + srow) * TT + 0) * 256 + sk;
    #pragma unroll
    for (int j = 0; j < 4; ++j) {
      xf[2*j]   = *(const f32x4*)(x_b0 + j*64);
      xf[2*j+1] = *(const f32x4*)(x_b0 + j*64 + 4);
    }
  }
  #pragma unroll
  for (int q_ = 0; q_ < 8; ++q_) { h0p[q_].u[0] = 0ull; h0p[q_].u[1] = 0ull; }

  // ==================== main recurrence ====================
  for (int t = 0; t < TT; ++t) {
    const int cur = t & 1;

    // ---- L0 part A: chunks 0..11 (x regs, h0_prev regs) ----
    acce = f32x4{0,0,0,0}; acco = f32x4{0,0,0,0};
    stageA(0, cvt8(xf[0], xf[1]));
    __syncthreads();
    #pragma unroll
    for (int j = 0; j < 12; ++j) {
      const int jn = j + 1;
      if (jn < 4)       stageA(jn & 1, cvt8(xf[2*jn], xf[2*jn+1]));
      else if (jn < 12) stageA(jn & 1, h0p[jn-4].v);
      mfma2(&Abuf[j & 1][mu*16 + ra][0], &W0s[nu*16 + ra][j*64]);
      __syncthreads();
    }

    // ---- Q(t-1): hides cntB fan-in under L0 partA; fills ctl + h1c regs ----
    if (t > 0) {
      qphase(t - 1);
    } else {
      #pragma unroll
      for (int q_ = 0; q_ < 8; ++q_) { h1c[q_].u[0] = 0ull; h1c[q_].u[1] = 0ull; }
    }

    // ---- L0 part B: ct chunks 12..13 from ctl + cell 0 ----
    mfma2(&ctl[mu*16 + ra][0],  &W0s[nu*16 + ra][768]);
    mfma2(&ctl[mu*16 + ra][64], &W0s[nu*16 + ra][832]);
    {
      f32x4 a = acce + acco;
      #pragma unroll
      for (int r = 0; r < 4; ++r) glds[mu*16 + crow + r][nu*16 + ra] = a[r];
    }
    __syncthreads();
    {
      float gI = glds[srow][ehc]      + bi0;
      float gF = glds[srow][8 + ehc]  + bf0;
      float gG = glds[srow][16 + ehc] + bg0;
      float gO = glds[srow][24 + ehc] + bo0;
      float cn = fsig(gF) * c0r + fsig(gI) * ftanh(gG);
      c0r = cn;
      hstage[srow][ehc] = (f16)(fsig(gO) * ftanh(cn));
    }
    __syncthreads();
    if (wv == 0) {                     // coalesced 1KB publish: lane -> 16B contiguous
      f16* pb = hpub(h0blk, cur);
      uint64_t u0 = *(uint64_t*)&hstage[lane][0];
      uint64_t u1 = *(uint64_t*)&hstage[lane][4];
      astore64(pb + lane*8,     u0);
      astore64(pb + lane*8 + 4, u1);
      asm volatile("s_waitcnt vmcnt(0)" ::: "memory");
      if (lane == 0) flag_add_relaxed(&cntA[(m << 9) + t]);
    }

    // ---- L1: chunks 0..7 (h1_prev regs), 8..15 (h0_cur); x(t+1) prefetch at j==6 ----
    acce = f32x4{0,0,0,0}; acco = f32x4{0,0,0,0};
    stageA(0, h1c[0].v);
    __syncthreads();
    #pragma unroll
    for (int j = 0; j < 16; ++j) {
      if (j == 6) {
        spin(&cntA[(m << 9) + t], 64u);
        const f16* h0c_b = hrd(h0blk, cur);
        #pragma unroll
        for (int q_ = 0; q_ < 8; ++q_) {
          h0c[q_].u[0] = aload64(h0c_b + q_*4096);
          h0c[q_].u[1] = aload64(h0c_b + q_*4096 + 4);
        }
        const int tn = (t + 1 < TT) ? t + 1 : t;   // x prefetch (clamped at tail)
        const float* x_bn = states + ((size_t)(m*64 + srow) * TT + tn) * 256 + sk;
        #pragma unroll
        for (int jq = 0; jq < 4; ++jq) {
          xfn[2*jq]   = *(const f32x4*)(x_bn + jq*64);
          xfn[2*jq+1] = *(const f32x4*)(x_bn + jq*64 + 4);
        }
      }
      const int jn = j + 1;
      if (jn < 8)       stageA(jn & 1, h1c[jn].v);
      else if (jn < 16) stageA(jn & 1, h0c[jn-8].v);
      mfma2(&Abuf[j & 1][mu*16 + ra][0], &W1s[nu*16 + ra][j*64]);
      __syncthreads();
    }
    {
      f32x4 a = acce + acco;
      #pragma unroll
      for (int r = 0; r < 4; ++r) glds[mu*16 + crow + r][nu*16 + ra] = a[r];
    }
    __syncthreads();
    {
      float gI = glds[srow][ehc]      + bi1;
      float gF = glds[srow][8 + ehc]  + bf1;
      float gG = glds[srow][16 + ehc] + bg1;
      float gO = glds[srow][24 + ehc] + bo1;
      float cn = fsig(gF) * c1r + fsig(gI) * ftanh(gG);
      c1r = cn;
      hstage[srow][ehc] = (f16)(fsig(gO) * ftanh(cn));
    }
    __syncthreads();
    if (wv == 0) {
      f16* pb = hpub(h1blk, cur);
      uint64_t u0 = *(uint64_t*)&hstage[lane][0];
      uint64_t u1 = *(uint64_t*)&hstage[lane][4];
      astore64(pb + lane*8,     u0);
      astore64(pb + lane*8 + 4, u1);
      asm volatile("s_waitcnt vmcnt(0)" ::: "memory");
      if (lane == 0) flag_add_relaxed(&cntB[(m << 9) + t]);
    }

    // ---- rotate register state for next step ----
    #pragma unroll
    for (int q_ = 0; q_ < 8; ++q_) h0p[q_] = h0c[q_];
    #pragma unroll
    for (int j = 0; j < 8; ++j) xf[j] = xfn[j];
  }

  // ---- tail: final Q for t = TT-1 ----
  qphase(TT - 1);
}

// ---------------- host ----------------
extern "C" void kernel_launch(void* const* d_in, const int* in_sizes, int n_in,
                              void* d_out, int out_size, void* d_ws, size_t ws_size,
                              hipStream_t stream) {
  const float* states = (const float*)d_in[0];
  const float* Wih0 = (const float*)d_in[1];
  const float* Whh0 = (const float*)d_in[2];
  const float* bih0 = (const float*)d_in[3];
  const float* bhh0 = (const float*)d_in[4];
  const float* Wih1 = (const float*)d_in[5];
  const float* Whh1 = (const float*)d_in[6];
  const float* bih1 = (const float*)d_in[7];
  const float* bhh1 = (const float*)d_in[8];
  const float* Wlin = (const float*)d_in[9];
  const float* blin = (const float*)d_in[10];
  float* out = (float*)d_out;
  (void)in_sizes; (void)n_in; (void)out_size;

  char* ws = (char*)d_ws;
  uint32_t* cntA = (uint32_t*)ws;                       // [4][512] = 8192 B
  uint32_t* cntB = (uint32_t*)(ws + 8192);              // 8192 B
  uint32_t* cnt0 = (uint32_t*)(ws + 16384);             // 4 B (pad to 256)
  const size_t cnt_bytes = 16640;
  f16* h0blk = (f16*)(ws + cnt_bytes);                  // 524,288 B (blocked layout)
  f16* h1blk = (f16*)(ws + cnt_bytes + 524288);         // 524,288 B
  f16* Wlc   = (f16*)(ws + cnt_bytes + 2 * 524288);     // 131,072 B
  float* noise = (float*)(ws + cnt_bytes + 2 * 524288 + 131072);  // 67,108,864 B
  const size_t need = cnt_bytes + 2 * 524288 + 131072 + 67108864;

  hipMemsetAsync(ws, 0, cnt_bytes, stream);
  if (ws_size >= need) {
    persistent_kernel<true><<<256, 512, 0, stream>>>(
        states, Wih0, Whh0, bih0, bhh0, Wih1, Whh1, bih1, bhh1, Wlin, blin,
        out, cnt0, cntA, cntB, h0blk, h1blk, Wlc, noise);
  } else {
    persistent_kernel<false><<<256, 512, 0, stream>>>(
        states, Wih0, Whh0, bih0, bhh0, Wih1, Whh1, bih1, bhh1, Wlin, blin,
        out, cnt0, cntA, cntB, h0blk, h1blk, Wlc, nullptr);
  }
}